// Round 18
// baseline (270.777 us; speedup 1.0000x reference)
//
#include <hip/hip_runtime.h>

typedef unsigned short u16;
typedef _Float16 f16;
typedef _Float16 f16x8 __attribute__((ext_vector_type(8)));
typedef float f32x4 __attribute__((ext_vector_type(4)));
typedef unsigned short u16x4 __attribute__((ext_vector_type(4)));
typedef unsigned int u32x4 __attribute__((ext_vector_type(4)));

__device__ __forceinline__ u16 f2h(float f) {
    f16 h = (f16)f;
    return *reinterpret_cast<u16*>(&h);
}
__device__ __forceinline__ float h2f(u16 u) {
    f16 h = *reinterpret_cast<f16*>(&u);
    return (float)h;
}

// 2^x via the native TRANS op, compiler-visible (hazard-safe)
__device__ __forceinline__ float exp2v(float x) { return __builtin_amdgcn_exp2f(x); }

// pack two f32 -> two fp16 in one u32 (RTZ), single VALU op
__device__ __forceinline__ unsigned cvtpkh(float lo, float hi) {
    unsigned r;
    asm("v_cvt_pkrtz_f16_f32 %0, %1, %2" : "=v"(r) : "v"(lo), "v"(hi));
    return r;
}

// async global -> LDS, 16B per lane; LDS dest is wave-uniform base + lane*16
__device__ __forceinline__ void gload16(const u16* g, u16* l) {
    __builtin_amdgcn_global_load_lds((const __attribute__((address_space(1))) unsigned int*)g,
                                     (__attribute__((address_space(3))) unsigned int*)l, 16, 0, 0);
}

#define RAW_BARRIER() __builtin_amdgcn_s_barrier()
#define WAITCNT_VM(N) asm volatile("s_waitcnt vmcnt(" #N ")" ::: "memory")

// XCD-chunked block id remap (bijective: all grids used are multiples of 8)
__device__ __forceinline__ int xcd_swz(int bid, int nwg) {
    return (bid & 7) * (nwg >> 3) + (bid >> 3);
}

// ---------------- transpose + cast fp32 -> fp16, Wt[n][k] = W[k][n]; z selects among 3 ----------------
__global__ void transpose_cast3(const float* __restrict__ W0, u16* __restrict__ T0,
                                const float* __restrict__ W1, u16* __restrict__ T1,
                                const float* __restrict__ W2, u16* __restrict__ T2,
                                int K, int N) {
    __shared__ float t[32][33];
    const float* W = (blockIdx.z == 0) ? W0 : (blockIdx.z == 1) ? W1 : W2;
    u16* Wt = (blockIdx.z == 0) ? T0 : (blockIdx.z == 1) ? T1 : T2;
    const int n0 = blockIdx.x * 32, k0 = blockIdx.y * 32;
    const int tx = threadIdx.x, ty = threadIdx.y;
#pragma unroll
    for (int i = 0; i < 32; i += 8)
        t[ty + i][tx] = W[(size_t)(k0 + ty + i) * N + n0 + tx];
    __syncthreads();
#pragma unroll
    for (int i = 0; i < 32; i += 8)
        Wt[(size_t)(n0 + ty + i) * K + k0 + tx] = f2h(t[tx][ty + i]);
}

__global__ void transpose_cast(const float* __restrict__ W, u16* __restrict__ Wt,
                               int K, int N) {
    __shared__ float t[32][33];
    const int n0 = blockIdx.x * 32, k0 = blockIdx.y * 32;
    const int tx = threadIdx.x, ty = threadIdx.y;
#pragma unroll
    for (int i = 0; i < 32; i += 8)
        t[ty + i][tx] = W[(size_t)(k0 + ty + i) * N + n0 + tx];
    __syncthreads();
#pragma unroll
    for (int i = 0; i < 32; i += 8)
        Wt[(size_t)(n0 + ty + i) * K + k0 + tx] = f2h(t[tx][ty + i]);
}

// ---------------- LayerNorm fp32 -> fp16, D=1024, one block per row ----------------
__global__ __launch_bounds__(256) void ln_f32_f16(const float* __restrict__ in,
                                                  const float* __restrict__ g,
                                                  const float* __restrict__ b,
                                                  u16* __restrict__ out) {
    constexpr int Dl = 1024;
    const int row = blockIdx.x, tid = threadIdx.x;
    const float4 v = *(const float4*)&in[(size_t)row * Dl + tid * 4];
    const float* vp = (const float*)&v;
    float s = v.x + v.y + v.z + v.w;
    float s2 = v.x * v.x + v.y * v.y + v.z * v.z + v.w * v.w;
#pragma unroll
    for (int off = 32; off; off >>= 1) { s += __shfl_xor(s, off); s2 += __shfl_xor(s2, off); }
    __shared__ float red[8];
    const int lane = tid & 63, wid = tid >> 6;
    if (lane == 0) { red[wid] = s; red[4 + wid] = s2; }
    __syncthreads();
    s = red[0] + red[1] + red[2] + red[3];
    s2 = red[4] + red[5] + red[6] + red[7];
    const float mean = s * (1.0f / Dl);
    const float rstd = rsqrtf(s2 * (1.0f / Dl) - mean * mean + 1e-5f);
    u16x4 pk;
#pragma unroll
    for (int i = 0; i < 4; ++i) {
        const int col = tid * 4 + i;
        pk[i] = f2h((vp[i] - mean) * rstd * g[col] + b[col]);
    }
    *(u16x4*)&out[(size_t)row * Dl + tid * 4] = pk;
}

// ---------------- LayerNorm + ReLU in-place on fp16, F=4096 ----------------
__global__ __launch_bounds__(256) void ln_relu_f16(u16* __restrict__ mid,
                                                   const float* __restrict__ g,
                                                   const float* __restrict__ b) {
    constexpr int Fl = 4096;
    const int row = blockIdx.x, tid = threadIdx.x;
    u16* rp = mid + (size_t)row * Fl;
    float v[16];
    u32x4 raw[2];
#pragma unroll
    for (int c = 0; c < 2; ++c) raw[c] = *(const u32x4*)&rp[tid * 16 + c * 8];
#pragma unroll
    for (int c = 0; c < 2; ++c)
#pragma unroll
        for (int j = 0; j < 4; ++j) {
            const unsigned u = raw[c][j];
            v[c * 8 + j * 2] = h2f((u16)(u & 0xffffu));
            v[c * 8 + j * 2 + 1] = h2f((u16)(u >> 16));
        }
    float s = 0.f, s2 = 0.f;
#pragma unroll
    for (int i = 0; i < 16; ++i) { s += v[i]; s2 += v[i] * v[i]; }
#pragma unroll
    for (int off = 32; off; off >>= 1) { s += __shfl_xor(s, off); s2 += __shfl_xor(s2, off); }
    __shared__ float red[8];
    const int lane = tid & 63, wid = tid >> 6;
    if (lane == 0) { red[wid] = s; red[4 + wid] = s2; }
    __syncthreads();
    s = red[0] + red[1] + red[2] + red[3];
    s2 = red[4] + red[5] + red[6] + red[7];
    const float mean = s * (1.0f / Fl);
    const float rstd = rsqrtf(s2 * (1.0f / Fl) - mean * mean + 1e-5f);
    unsigned w[8];
#pragma unroll
    for (int j = 0; j < 8; ++j) {
        const int col = tid * 16 + j * 2;
        const float y0 = fmaxf((v[j * 2] - mean) * rstd * g[col] + b[col], 0.f);
        const float y1 = fmaxf((v[j * 2 + 1] - mean) * rstd * g[col + 1] + b[col + 1], 0.f);
        w[j] = (unsigned)f2h(y0) | ((unsigned)f2h(y1) << 16);
    }
    *(u32x4*)&rp[tid * 16] = *(u32x4*)&w[0];
    *(u32x4*)&rp[tid * 16 + 8] = *(u32x4*)&w[4];
}

// ---------------- fp16 MFMA GEMM, 2-phase dbuf, m-major XCD chunking ----------------
// LDS granule swizzle: source pre-swizzled, LDS dest linear, read col = 8*(fgrp ^ ((fr>>1)&3)).
// EPI 0: fp16 row-major out   1: f32 row-major out
template <int EPI, int BN>
__global__ __launch_bounds__(256, 4) void gemm_f16(const u16* __restrict__ A,
                                                   const u16* __restrict__ Bt,
                                                   const float* __restrict__ bias,
                                                   u16* __restrict__ outB,
                                                   float* __restrict__ outF,
                                                   int M_, int N_, int K_) {
    constexpr int BK = 32;
    constexpr int NJ = BN / 32;
    __shared__ u16 As[2][128 * BK];
    __shared__ u16 Bs[2][BN * BK];
    const int tid = threadIdx.x;
    const int lane = tid & 63;
    const int wid = tid >> 6;
    const int swz = xcd_swz(blockIdx.y * gridDim.x + blockIdx.x, gridDim.x * gridDim.y);
    const int m0 = (swz / gridDim.x) * 128;
    const int n0 = (swz % gridDim.x) * BN;
    const int wr = (wid >> 1) * 64;
    const int wc = (wid & 1) * (BN / 2);
    const int fr = lane & 15;
    const int fg = 8 * ((lane >> 4) ^ ((fr >> 1) & 3));  // swizzled read col

    const int srow = wid * 32 + (lane >> 2);
    const int srB = wid * (BN / 4) + (lane >> 2);
    const int scol = 8 * ((lane & 3) ^ ((lane >> 3) & 3));  // pre-swizzled source col
    const u16* pa0 = A + (size_t)(m0 + srow) * K_ + scol;
    const u16* pa1 = pa0 + (size_t)16 * K_;
    const u16* pb0 = Bt + (size_t)(n0 + srB) * K_ + scol;
    const u16* pb1 = pb0 + (size_t)16 * K_;
    const int aoff = wid * 1024;
    const int boff = wid * (BN / 4) * BK;

    auto stage = [&](int k0, int buf) {
        gload16(pa0 + k0, &As[buf][aoff]);
        gload16(pa1 + k0, &As[buf][aoff + 512]);
        gload16(pb0 + k0, &Bs[buf][boff]);
        if constexpr (BN == 128) gload16(pb1 + k0, &Bs[buf][boff + 512]);
    };

    f32x4 acc[4][NJ] = {};
    const int nt = K_ / BK;

    stage(0, 0);
    WAITCNT_VM(0);
    RAW_BARRIER();

    for (int t = 0; t < nt; ++t) {
        const int buf = t & 1;
        if (t + 1 < nt) stage((t + 1) * BK, buf ^ 1);
        f16x8 aF[4], bF[NJ];
#pragma unroll
        for (int i = 0; i < 4; ++i) aF[i] = *(const f16x8*)&As[buf][(wr + i * 16 + fr) * BK + fg];
#pragma unroll
        for (int j = 0; j < NJ; ++j) bF[j] = *(const f16x8*)&Bs[buf][(wc + j * 16 + fr) * BK + fg];
#pragma unroll
        for (int i = 0; i < 4; ++i)
#pragma unroll
            for (int j = 0; j < NJ; ++j)
                acc[i][j] = __builtin_amdgcn_mfma_f32_16x16x32_f16(aF[i], bF[j], acc[i][j], 0, 0, 0);
        WAITCNT_VM(0);
        RAW_BARRIER();
    }

    const int g4 = (lane >> 4) * 4;
#pragma unroll
    for (int i = 0; i < 4; ++i) {
#pragma unroll
        for (int j = 0; j < NJ; ++j) {
            const int mb = m0 + wr + i * 16 + g4;
            const int nb = n0 + wc + j * 16 + fr;
            const float bv = bias[nb];
            if constexpr (EPI == 0) {
#pragma unroll
                for (int r = 0; r < 4; ++r)
                    outB[(size_t)(mb + r) * N_ + nb] = f2h(acc[i][j][r] + bv);
            } else {
#pragma unroll
                for (int r = 0; r < 4; ++r)
                    outF[(size_t)(mb + r) * N_ + nb] = acc[i][j][r] + bv;
            }
        }
    }
}

// ---------- split-K fp16 GEMM (MLP2): partial f32 (no bias), blockIdx.z = K half ----------
__global__ __launch_bounds__(256, 4) void gemm_f16_splitk(const u16* __restrict__ A,
                                                          const u16* __restrict__ Bt,
                                                          float* __restrict__ p0,
                                                          float* __restrict__ p1,
                                                          int M_, int N_, int K_) {
    constexpr int BK = 32, BN = 64;
    __shared__ u16 As[2][128 * BK];
    __shared__ u16 Bs[2][BN * BK];
    const int tid = threadIdx.x;
    const int lane = tid & 63;
    const int wid = tid >> 6;
    const int swz = xcd_swz(blockIdx.y * gridDim.x + blockIdx.x, gridDim.x * gridDim.y);
    const int m0 = (swz / gridDim.x) * 128;
    const int n0 = (swz % gridDim.x) * BN;
    const int kBase = blockIdx.z * (K_ >> 1);
    float* dst = blockIdx.z ? p1 : p0;
    const int wr = (wid >> 1) * 64;
    const int wc = (wid & 1) * (BN / 2);
    const int fr = lane & 15;
    const int fg = 8 * ((lane >> 4) ^ ((fr >> 1) & 3));

    const int srow = wid * 32 + (lane >> 2);
    const int srB = wid * (BN / 4) + (lane >> 2);
    const int scol = 8 * ((lane & 3) ^ ((lane >> 3) & 3));
    const u16* pa0 = A + (size_t)(m0 + srow) * K_ + kBase + scol;
    const u16* pa1 = pa0 + (size_t)16 * K_;
    const u16* pb0 = Bt + (size_t)(n0 + srB) * K_ + kBase + scol;
    const int aoff = wid * 1024;
    const int boff = wid * (BN / 4) * BK;

    auto stage = [&](int k0, int buf) {
        gload16(pa0 + k0, &As[buf][aoff]);
        gload16(pa1 + k0, &As[buf][aoff + 512]);
        gload16(pb0 + k0, &Bs[buf][boff]);
    };

    f32x4 acc[4][2] = {};
    const int nt = (K_ >> 1) / BK;

    stage(0, 0);
    WAITCNT_VM(0);
    RAW_BARRIER();

    for (int t = 0; t < nt; ++t) {
        const int buf = t & 1;
        if (t + 1 < nt) stage((t + 1) * BK, buf ^ 1);
        f16x8 aF[4], bF[2];
#pragma unroll
        for (int i = 0; i < 4; ++i) aF[i] = *(const f16x8*)&As[buf][(wr + i * 16 + fr) * BK + fg];
#pragma unroll
        for (int j = 0; j < 2; ++j) bF[j] = *(const f16x8*)&Bs[buf][(wc + j * 16 + fr) * BK + fg];
#pragma unroll
        for (int i = 0; i < 4; ++i)
#pragma unroll
            for (int j = 0; j < 2; ++j)
                acc[i][j] = __builtin_amdgcn_mfma_f32_16x16x32_f16(aF[i], bF[j], acc[i][j], 0, 0, 0);
        WAITCNT_VM(0);
        RAW_BARRIER();
    }

    const int g4 = (lane >> 4) * 4;
#pragma unroll
    for (int i = 0; i < 4; ++i)
#pragma unroll
        for (int j = 0; j < 2; ++j) {
            const int mb = m0 + wr + i * 16 + g4;
            const int nb = n0 + wc + j * 16 + fr;
#pragma unroll
            for (int r = 0; r < 4; ++r)
                dst[(size_t)(mb + r) * N_ + nb] = acc[i][j][r];
        }
}

// ---------- reduce: out = p0 + p1 + bias (f32, vectorized) ----------
__global__ __launch_bounds__(256) void reduce2_bias(const float* __restrict__ p0,
                                                    const float* __restrict__ p1,
                                                    const float* __restrict__ bias,
                                                    float* __restrict__ out, int N_) {
    const size_t i4 = (size_t)blockIdx.x * 256 + threadIdx.x;  // float4 index
    const float4 a = ((const float4*)p0)[i4];
    const float4 b = ((const float4*)p1)[i4];
    const int col4 = (int)(i4 % (N_ / 4));
    const float4 bi = ((const float4*)bias)[col4];
    float4 o;
    o.x = a.x + b.x + bi.x;
    o.y = a.y + b.y + bi.y;
    o.z = a.z + b.z + bi.z;
    o.w = a.w + b.w + bi.w;
    ((float4*)out)[i4] = o;
}

// ------------- fused QKV projection GEMM (fp16, 2-phase dbuf, m-major chunking) -------------
__global__ __launch_bounds__(256, 4) void gemm_qkv(const u16* __restrict__ A,
                                                   const u16* __restrict__ qW,
                                                   const u16* __restrict__ kW,
                                                   const u16* __restrict__ vW,
                                                   const float* __restrict__ bq,
                                                   const float* __restrict__ bk,
                                                   const float* __restrict__ bv,
                                                   u16* __restrict__ qb, u16* __restrict__ kb,
                                                   u16* __restrict__ vtb,
                                                   int M_, int K_) {
    constexpr int BK = 32;
    __shared__ u16 As[2][128 * BK];
    __shared__ u16 Bs[2][64 * BK];
    const int tid = threadIdx.x;
    const int lane = tid & 63;
    const int wid = tid >> 6;
    const int swz = xcd_swz(blockIdx.y * gridDim.x + blockIdx.x, gridDim.x * gridDim.y);
    const int bx = swz % gridDim.x;
    const int region = bx >> 4;  // 0=q 1=k 2=v (block-uniform)
    const int n0 = (bx & 15) * 64;
    const int m0 = (swz / gridDim.x) * 128;
    const int wr = (wid >> 1) * 64;
    const int wc = (wid & 1) * 32;
    const int fr = lane & 15;
    const int fg = 8 * ((lane >> 4) ^ ((fr >> 1) & 3));

    const int srow = wid * 32 + (lane >> 2);
    const int srB = wid * 16 + (lane >> 2);
    const int scol = 8 * ((lane & 3) ^ ((lane >> 3) & 3));

    const u16* B = (region == 0) ? qW : (region == 1) ? kW : vW;
    const u16* pa0 = A + (size_t)(m0 + srow) * K_ + scol;
    const u16* pa1 = pa0 + (size_t)16 * K_;
    const u16* pb = B + (size_t)(n0 + srB) * K_ + scol;
    const int aoff = wid * 1024;
    const int boff = wid * 512;

    auto stage = [&](int k0, int buf) {
        gload16(pa0 + k0, &As[buf][aoff]);
        gload16(pa1 + k0, &As[buf][aoff + 512]);
        gload16(pb + k0, &Bs[buf][boff]);
    };

    f32x4 acc[4][2] = {};
    const int nt = K_ / BK;

    stage(0, 0);
    WAITCNT_VM(0);
    RAW_BARRIER();

    for (int t = 0; t < nt; ++t) {
        const int buf = t & 1;
        if (t + 1 < nt) stage((t + 1) * BK, buf ^ 1);
        f16x8 aF[4], bF[2];
#pragma unroll
        for (int i = 0; i < 4; ++i) aF[i] = *(const f16x8*)&As[buf][(wr + i * 16 + fr) * BK + fg];
#pragma unroll
        for (int j = 0; j < 2; ++j) bF[j] = *(const f16x8*)&Bs[buf][(wc + j * 16 + fr) * BK + fg];
#pragma unroll
        for (int i = 0; i < 4; ++i)
#pragma unroll
            for (int j = 0; j < 2; ++j)
                acc[i][j] = __builtin_amdgcn_mfma_f32_16x16x32_f16(aF[i], bF[j], acc[i][j], 0, 0, 0);
        WAITCNT_VM(0);
        RAW_BARRIER();
    }

    const float* bias = (region == 0) ? bq : (region == 1) ? bk : bv;
    const float scale = (region == 0) ? 32.f : 1.f;
    const int g4 = (lane >> 4) * 4;
#pragma unroll
    for (int i = 0; i < 4; ++i) {
#pragma unroll
        for (int j = 0; j < 2; ++j) {
            const int mb = m0 + wr + i * 16 + g4;
            const int nb = n0 + wc + j * 16 + fr;
            const float bv_ = bias[nb];
            const int h = nb >> 6, e = nb & 63;
            if (region < 2) {
                u16* outp = (region == 0) ? qb : kb;
#pragma unroll
                for (int r = 0; r < 4; ++r) {
                    const int m = mb + r;
                    const size_t idx = ((size_t)((m >> 11) * 16 + h) * 2048 + (m & 2047)) * 64 + e;
                    outp[idx] = f2h((acc[i][j][r] + bv_) * scale);
                }
            } else {
                const int b_ = mb >> 11, np = mb & 2047;
                u16x4 pk;
#pragma unroll
                for (int r = 0; r < 4; ++r) pk[r] = f2h(acc[i][j][r] + bv_);
                *(u16x4*)&vtb[((size_t)(b_ * 16 + h) * 64 + e) * 2048 + np] = pk;
            }
        }
    }
}

// ---------------- flash attention, KV-split by 2: per-half normalized o' + (m,l) ----------------
// 1024 blocks: swzb -> {qc, half, bh}. Each block: 128 q-rows, KV range [half*1024, +1024).
// Emits op[half][bh][n][e] (fp16, o/l), mA/lA[half*65536 + bh*2048 + n] (f32).
__global__ __launch_bounds__(512, 3) void attn_kernel(const u16* __restrict__ q,
                                                      const u16* __restrict__ k,
                                                      const u16* __restrict__ vt,
                                                      u16* __restrict__ op,
                                                      float* __restrict__ mA,
                                                      float* __restrict__ lA) {
    constexpr int N = 2048, E = 64, KB = 64, NT = 16;  // 16 tiles = half the KV range
    constexpr float L2E = 1.4426950408889634f;
    __shared__ u16 Ks[2][64 * 64];
    __shared__ u16 Vs[2][64 * 64];
    __shared__ unsigned Ps[8][16][36];  // u32 view of P[q=16][k=64] fp16, row stride 144B

    const int tid = threadIdx.x;
    const int lane = tid & 63;
    const int wid = tid >> 6;
    const int swzb = xcd_swz(blockIdx.x, gridDim.x);
    const int q0 = (swzb & 15) * 128;
    const int half = (swzb >> 4) & 1;
    const int bh = swzb >> 5;
    const int kv0 = half * 1024;
    const u16* qh = q + (size_t)bh * N * E;
    const u16* kh = k + (size_t)bh * N * E;
    const u16* vh = vt + (size_t)bh * E * N;

    const int fr = lane & 15;
    const int fgrp = lane >> 4;
    const int fg8 = fgrp * 8;
    int pc[2];
#pragma unroll
    for (int ks = 0; ks < 2; ++ks) pc[ks] = 8 * (((ks << 2) + fgrp) ^ (fr & 7));

    const int srow = wid * 8 + (lane >> 3);
    const int swc = 8 * ((lane & 7) ^ (lane >> 3));  // pre-swizzled source col
    u16* dK = &Ks[0][wid * 8 * 64];
    u16* dV = &Vs[0][wid * 8 * 64];
    constexpr int BUFO = 64 * 64;

    f16x8 qf[2];
#pragma unroll
    for (int ks = 0; ks < 2; ++ks)
        qf[ks] = *(const f16x8*)&qh[(size_t)(q0 + wid * 16 + fr) * E + ks * 32 + fg8];

    auto stage = [&](int t, int buf) {
        const size_t kb = (size_t)kv0 + (size_t)t * KB;
        gload16(kh + (kb + srow) * E + swc, dK + buf * BUFO);
        gload16(vh + (size_t)srow * N + kb + swc, dV + buf * BUFO);
    };

    f32x4 o[4] = {};
    float mrow = -1e30f, lpart = 0.f;  // per-lane state for q-row (wid*16 + fr)

    stage(0, 0);

    for (int t = 0; t < NT; ++t) {
        const int buf = t & 1;
        RAW_BARRIER();
        if (t + 1 < NT) {
            stage(t + 1, buf ^ 1);
            WAITCNT_VM(2);
        } else {
            WAITCNT_VM(0);
        }
        RAW_BARRIER();

        const u16* KK = &Ks[buf][0];
        const u16* VV = &Vs[buf][0];

        // S^T = K . Q^T : lane holds q-row = wid*16+fr, kpos = fn*16 + fgrp*4 + r
        f32x4 s[4] = {};
        __builtin_amdgcn_s_setprio(1);
#pragma unroll
        for (int fn = 0; fn < 4; ++fn)
#pragma unroll
            for (int ks = 0; ks < 2; ++ks) {
                const f16x8 kf = *(const f16x8*)&KK[(fn * 16 + fr) * 64 + pc[ks]];
                s[fn] = __builtin_amdgcn_mfma_f32_16x16x32_f16(kf, qf[ks], s[fn], 0, 0, 0);
            }
        __builtin_amdgcn_s_setprio(0);

        float lmax = fmaxf(fmaxf(fmaxf(s[0][0], s[0][1]), fmaxf(s[0][2], s[0][3])),
                           fmaxf(fmaxf(s[1][0], s[1][1]), fmaxf(s[1][2], s[1][3])));
        lmax = fmaxf(lmax, fmaxf(fmaxf(fmaxf(s[2][0], s[2][1]), fmaxf(s[2][2], s[2][3])),
                                 fmaxf(fmaxf(s[3][0], s[3][1]), fmaxf(s[3][2], s[3][3]))));
        if (!__all(lmax <= mrow + 8.f)) {
            float m2 = fmaxf(lmax, __shfl_xor(lmax, 16));
            m2 = fmaxf(m2, __shfl_xor(m2, 32));
            const float mnew = fmaxf(mrow, m2);
            const float fac = exp2v((mrow - mnew) * L2E);
            mrow = mnew;
            lpart *= fac;
            float fo[4];
#pragma unroll
            for (int r = 0; r < 4; ++r) fo[r] = __shfl(fac, fgrp * 4 + r);
#pragma unroll
            for (int fe = 0; fe < 4; ++fe)
#pragma unroll
                for (int r = 0; r < 4; ++r) o[fe][r] *= fo[r];
        }

        const float nml = -mrow * L2E;
#pragma unroll
        for (int fn = 0; fn < 4; ++fn) {
            const float p0 = exp2v(fmaf(s[fn][0], L2E, nml));
            const float p1 = exp2v(fmaf(s[fn][1], L2E, nml));
            const float p2 = exp2v(fmaf(s[fn][2], L2E, nml));
            const float p3 = exp2v(fmaf(s[fn][3], L2E, nml));
            lpart += (p0 + p1) + (p2 + p3);
            uint2 w;
            w.x = cvtpkh(p0, p1);
            w.y = cvtpkh(p2, p3);
            *(uint2*)&Ps[wid][fr][fn * 8 + fgrp * 2] = w;
        }

        const u16* prow = (const u16*)&Ps[wid][fr][0];
        f16x8 pf[2];
#pragma unroll
        for (int ks = 0; ks < 2; ++ks) pf[ks] = *(const f16x8*)&prow[ks * 32 + fg8];
        __builtin_amdgcn_s_setprio(1);
#pragma unroll
        for (int fe = 0; fe < 4; ++fe)
#pragma unroll
            for (int ks = 0; ks < 2; ++ks) {
                const f16x8 vf = *(const f16x8*)&VV[(fe * 16 + fr) * 64 + pc[ks]];
                o[fe] = __builtin_amdgcn_mfma_f32_16x16x32_f16(pf[ks], vf, o[fe], 0, 0, 0);
            }
        __builtin_amdgcn_s_setprio(0);
    }

    float lsum = lpart + __shfl_xor(lpart, 16);
    lsum += __shfl_xor(lsum, 32);

    // per q-row stats (mrow/lsum are uniform across the 4 fgrp replicas)
    const int rowg = (half * 32 + bh) * 2048 + q0 + wid * 16;
    if (fgrp == 0) {
        mA[rowg + fr] = mrow;
        lA[rowg + fr] = lsum;
    }

    float rl[4];
#pragma unroll
    for (int r = 0; r < 4; ++r) rl[r] = 1.0f / __shfl(lsum, fgrp * 4 + r);

#pragma unroll
    for (int fe = 0; fe < 4; ++fe)
#pragma unroll
        for (int r = 0; r < 4; ++r)
            op[((size_t)rowg + fgrp * 4 + r) * 64 + fe * 16 + fr] = f2h(o[fe][r] * rl[r]);
}

// ---------------- flash combine + residual: x2 = x + merge(o0', o1') ----------------
__global__ __launch_bounds__(256) void attn_combine(const u16* __restrict__ op,
                                                    const float* __restrict__ mA,
                                                    const float* __restrict__ lA,
                                                    const float* __restrict__ x,
                                                    float* __restrict__ x2) {
    constexpr float L2E = 1.4426950408889634f;
    const int gid = blockIdx.x * 256 + threadIdx.x;  // 1M threads: 65536 rows x 16
    const int row = gid >> 4;                        // bh*2048 + n
    const int e0 = (gid & 15) * 4;
    const float m0 = mA[row], m1 = mA[65536 + row];
    const float l0 = lA[row], l1 = lA[65536 + row];
    const float m = fmaxf(m0, m1);
    const float w0 = l0 * exp2v((m0 - m) * L2E);
    const float w1 = l1 * exp2v((m1 - m) * L2E);
    const float inv = 1.0f / (w0 + w1);
    const float c0 = w0 * inv, c1 = w1 * inv;

    const size_t oi = (size_t)row * 64 + e0;
    const uint2 r0 = *(const uint2*)&op[oi];
    const uint2 r1 = *(const uint2*)&op[(size_t)65536 * 64 + oi];

    const int bh = row >> 11, n = row & 2047;
    const int b_ = bh >> 4, h_ = bh & 15;
    const size_t xi = ((size_t)(b_ * 2048 + n)) * 1024 + h_ * 64 + e0;
    const float4 xv = *(const float4*)&x[xi];
    float4 ov;
    ov.x = xv.x + c0 * h2f((u16)(r0.x & 0xffffu)) + c1 * h2f((u16)(r1.x & 0xffffu));
    ov.y = xv.y + c0 * h2f((u16)(r0.x >> 16)) + c1 * h2f((u16)(r1.x >> 16));
    ov.z = xv.z + c0 * h2f((u16)(r0.y & 0xffffu)) + c1 * h2f((u16)(r1.y & 0xffffu));
    ov.w = xv.w + c0 * h2f((u16)(r0.y >> 16)) + c1 * h2f((u16)(r1.y >> 16));
    *(float4*)&x2[xi] = ov;
}

// ---------------- launch ----------------
extern "C" void kernel_launch(void* const* d_in, const int* in_sizes, int n_in,
                              void* d_out, int out_size, void* d_ws, size_t ws_size,
                              hipStream_t stream) {
    const float* x = (const float*)d_in[0];
    const float* wq = (const float*)d_in[1];
    const float* bq = (const float*)d_in[2];
    const float* wk = (const float*)d_in[3];
    const float* bk = (const float*)d_in[4];
    const float* wv = (const float*)d_in[5];
    const float* bv = (const float*)d_in[6];
    const float* g1 = (const float*)d_in[7];
    const float* b1 = (const float*)d_in[8];
    const float* g2 = (const float*)d_in[9];
    const float* b2 = (const float*)d_in[10];
    const float* w1 = (const float*)d_in[11];
    const float* bw1 = (const float*)d_in[12];
    const float* gf = (const float*)d_in[13];
    const float* bf = (const float*)d_in[14];
    const float* w2 = (const float*)d_in[15];
    const float* bw2 = (const float*)d_in[16];
    float* out = (float*)d_out;

    constexpr int Bc = 2, Nc = 2048, Dc = 1024, Fc = 4096, Mc = 4096;

    char* ws = (char*)d_ws;
    auto alloc = [&](size_t bytes) {
        char* p = ws;
        ws += (bytes + 255) & ~(size_t)255;
        return p;
    };
    u16* wqt = (u16*)alloc((size_t)Dc * Dc * 2);
    u16* wkt = (u16*)alloc((size_t)Dc * Dc * 2);
    u16* wvt = (u16*)alloc((size_t)Dc * Dc * 2);
    u16* w1t = (u16*)alloc((size_t)Dc * Fc * 2);
    u16* w2t = (u16*)alloc((size_t)Fc * Dc * 2);
    // region holds h1, q, k, vT (4 x 8MB); mid (32MB) aliases it after attention
    char* region = (char*)alloc((size_t)Mc * Dc * 2 * 4);
    u16* h1 = (u16*)region;
    u16* qb = h1 + (size_t)Mc * Dc;
    u16* kb = qb + (size_t)Mc * Dc;
    u16* vtb = kb + (size_t)Mc * Dc;
    u16* mid = (u16*)region;
    float* x2 = (float*)alloc((size_t)Mc * Dc * 4);   // combine output; reused as p0 after LN2
    u16* h2 = (u16*)alloc((size_t)Mc * Dc * 2);
    float* p1 = (float*)alloc((size_t)Mc * Dc * 4);   // splitk partial; holds op during attention
    float* p0 = x2;
    u16* op = (u16*)p1;                               // 2*32*2048*64 fp16 = 16MB, dead before splitk
    float* mArr = (float*)alloc((size_t)2 * 32 * 2048 * 4);
    float* lArr = (float*)alloc((size_t)2 * 32 * 2048 * 4);

    const dim3 tb(32, 8);
    transpose_cast3<<<dim3(Dc / 32, Dc / 32, 3), tb, 0, stream>>>(wq, wqt, wk, wkt, wv, wvt, Dc, Dc);
    transpose_cast<<<dim3(Fc / 32, Dc / 32), tb, 0, stream>>>(w1, w1t, Dc, Fc);
    transpose_cast<<<dim3(Dc / 32, Fc / 32), tb, 0, stream>>>(w2, w2t, Fc, Dc);

    ln_f32_f16<<<Mc, 256, 0, stream>>>(x, g1, b1, h1);

    gemm_qkv<<<dim3(48, Mc / 128), 256, 0, stream>>>(h1, wqt, wkt, wvt, bq, bk, bv,
                                                     qb, kb, vtb, Mc, Dc);

    attn_kernel<<<Bc * 16 * (Nc / 128) * 2, 512, 0, stream>>>(qb, kb, vtb, op, mArr, lArr);
    attn_combine<<<(32 * Nc * 16) / 256, 256, 0, stream>>>(op, mArr, lArr, x, x2);

    ln_f32_f16<<<Mc, 256, 0, stream>>>(x2, g2, b2, h2);

    gemm_f16<0, 128><<<dim3(Fc / 128, Mc / 128), 256, 0, stream>>>(h2, w1t, bw1, mid, nullptr, Mc, Fc, Dc);

    ln_relu_f16<<<Mc, 256, 0, stream>>>(mid, gf, bf);

    gemm_f16_splitk<<<dim3(Dc / 64, Mc / 128, 2), 256, 0, stream>>>(mid, w2t, p0, p1, Mc, Dc, Fc);
    reduce2_bias<<<(Mc * Dc) / 1024, 256, 0, stream>>>(p0, p1, bw2, out, Dc);
}

// Round 19
// 264.887 us; speedup vs baseline: 1.0222x; 1.0222x over previous
//
#include <hip/hip_runtime.h>

typedef unsigned short u16;
typedef _Float16 f16;
typedef _Float16 f16x8 __attribute__((ext_vector_type(8)));
typedef float f32x4 __attribute__((ext_vector_type(4)));
typedef unsigned short u16x4 __attribute__((ext_vector_type(4)));
typedef unsigned int u32x4 __attribute__((ext_vector_type(4)));

__device__ __forceinline__ u16 f2h(float f) {
    f16 h = (f16)f;
    return *reinterpret_cast<u16*>(&h);
}
__device__ __forceinline__ float h2f(u16 u) {
    f16 h = *reinterpret_cast<f16*>(&u);
    return (float)h;
}

// 2^x via the native TRANS op, compiler-visible (hazard-safe)
__device__ __forceinline__ float exp2v(float x) { return __builtin_amdgcn_exp2f(x); }

// pack two f32 -> two fp16 in one u32 (RTZ), single VALU op
__device__ __forceinline__ unsigned cvtpkh(float lo, float hi) {
    unsigned r;
    asm("v_cvt_pkrtz_f16_f32 %0, %1, %2" : "=v"(r) : "v"(lo), "v"(hi));
    return r;
}

// async global -> LDS, 16B per lane; LDS dest is wave-uniform base + lane*16
__device__ __forceinline__ void gload16(const u16* g, u16* l) {
    __builtin_amdgcn_global_load_lds((const __attribute__((address_space(1))) unsigned int*)g,
                                     (__attribute__((address_space(3))) unsigned int*)l, 16, 0, 0);
}

#define RAW_BARRIER() __builtin_amdgcn_s_barrier()
#define WAITCNT_VM(N) asm volatile("s_waitcnt vmcnt(" #N ")" ::: "memory")

// XCD-chunked block id remap (bijective: all grids used are multiples of 8)
__device__ __forceinline__ int xcd_swz(int bid, int nwg) {
    return (bid & 7) * (nwg >> 3) + (bid >> 3);
}

// ---------------- transpose + cast fp32 -> fp16, Wt[n][k] = W[k][n]; z selects among 3 ----------------
__global__ void transpose_cast3(const float* __restrict__ W0, u16* __restrict__ T0,
                                const float* __restrict__ W1, u16* __restrict__ T1,
                                const float* __restrict__ W2, u16* __restrict__ T2,
                                int K, int N) {
    __shared__ float t[32][33];
    const float* W = (blockIdx.z == 0) ? W0 : (blockIdx.z == 1) ? W1 : W2;
    u16* Wt = (blockIdx.z == 0) ? T0 : (blockIdx.z == 1) ? T1 : T2;
    const int n0 = blockIdx.x * 32, k0 = blockIdx.y * 32;
    const int tx = threadIdx.x, ty = threadIdx.y;
#pragma unroll
    for (int i = 0; i < 32; i += 8)
        t[ty + i][tx] = W[(size_t)(k0 + ty + i) * N + n0 + tx];
    __syncthreads();
#pragma unroll
    for (int i = 0; i < 32; i += 8)
        Wt[(size_t)(n0 + ty + i) * K + k0 + tx] = f2h(t[tx][ty + i]);
}

__global__ void transpose_cast(const float* __restrict__ W, u16* __restrict__ Wt,
                               int K, int N) {
    __shared__ float t[32][33];
    const int n0 = blockIdx.x * 32, k0 = blockIdx.y * 32;
    const int tx = threadIdx.x, ty = threadIdx.y;
#pragma unroll
    for (int i = 0; i < 32; i += 8)
        t[ty + i][tx] = W[(size_t)(k0 + ty + i) * N + n0 + tx];
    __syncthreads();
#pragma unroll
    for (int i = 0; i < 32; i += 8)
        Wt[(size_t)(n0 + ty + i) * K + k0 + tx] = f2h(t[tx][ty + i]);
}

// ---------------- LayerNorm fp32 -> fp16, D=1024, one block per row ----------------
__global__ __launch_bounds__(256) void ln_f32_f16(const float* __restrict__ in,
                                                  const float* __restrict__ g,
                                                  const float* __restrict__ b,
                                                  u16* __restrict__ out) {
    constexpr int Dl = 1024;
    const int row = blockIdx.x, tid = threadIdx.x;
    const float4 v = *(const float4*)&in[(size_t)row * Dl + tid * 4];
    const float* vp = (const float*)&v;
    float s = v.x + v.y + v.z + v.w;
    float s2 = v.x * v.x + v.y * v.y + v.z * v.z + v.w * v.w;
#pragma unroll
    for (int off = 32; off; off >>= 1) { s += __shfl_xor(s, off); s2 += __shfl_xor(s2, off); }
    __shared__ float red[8];
    const int lane = tid & 63, wid = tid >> 6;
    if (lane == 0) { red[wid] = s; red[4 + wid] = s2; }
    __syncthreads();
    s = red[0] + red[1] + red[2] + red[3];
    s2 = red[4] + red[5] + red[6] + red[7];
    const float mean = s * (1.0f / Dl);
    const float rstd = rsqrtf(s2 * (1.0f / Dl) - mean * mean + 1e-5f);
    u16x4 pk;
#pragma unroll
    for (int i = 0; i < 4; ++i) {
        const int col = tid * 4 + i;
        pk[i] = f2h((vp[i] - mean) * rstd * g[col] + b[col]);
    }
    *(u16x4*)&out[(size_t)row * Dl + tid * 4] = pk;
}

// ---------------- LayerNorm + ReLU in-place on fp16, F=4096 ----------------
__global__ __launch_bounds__(256) void ln_relu_f16(u16* __restrict__ mid,
                                                   const float* __restrict__ g,
                                                   const float* __restrict__ b) {
    constexpr int Fl = 4096;
    const int row = blockIdx.x, tid = threadIdx.x;
    u16* rp = mid + (size_t)row * Fl;
    float v[16];
    u32x4 raw[2];
#pragma unroll
    for (int c = 0; c < 2; ++c) raw[c] = *(const u32x4*)&rp[tid * 16 + c * 8];
#pragma unroll
    for (int c = 0; c < 2; ++c)
#pragma unroll
        for (int j = 0; j < 4; ++j) {
            const unsigned u = raw[c][j];
            v[c * 8 + j * 2] = h2f((u16)(u & 0xffffu));
            v[c * 8 + j * 2 + 1] = h2f((u16)(u >> 16));
        }
    float s = 0.f, s2 = 0.f;
#pragma unroll
    for (int i = 0; i < 16; ++i) { s += v[i]; s2 += v[i] * v[i]; }
#pragma unroll
    for (int off = 32; off; off >>= 1) { s += __shfl_xor(s, off); s2 += __shfl_xor(s2, off); }
    __shared__ float red[8];
    const int lane = tid & 63, wid = tid >> 6;
    if (lane == 0) { red[wid] = s; red[4 + wid] = s2; }
    __syncthreads();
    s = red[0] + red[1] + red[2] + red[3];
    s2 = red[4] + red[5] + red[6] + red[7];
    const float mean = s * (1.0f / Fl);
    const float rstd = rsqrtf(s2 * (1.0f / Fl) - mean * mean + 1e-5f);
    unsigned w[8];
#pragma unroll
    for (int j = 0; j < 8; ++j) {
        const int col = tid * 16 + j * 2;
        const float y0 = fmaxf((v[j * 2] - mean) * rstd * g[col] + b[col], 0.f);
        const float y1 = fmaxf((v[j * 2 + 1] - mean) * rstd * g[col + 1] + b[col + 1], 0.f);
        w[j] = (unsigned)f2h(y0) | ((unsigned)f2h(y1) << 16);
    }
    *(u32x4*)&rp[tid * 16] = *(u32x4*)&w[0];
    *(u32x4*)&rp[tid * 16 + 8] = *(u32x4*)&w[4];
}

// ---------------- fp16 MFMA GEMM, 2-phase dbuf, m-major XCD chunking ----------------
// LDS granule swizzle: source pre-swizzled, LDS dest linear, read col = 8*(fgrp ^ ((fr>>1)&3)).
// EPI 0: fp16 row-major out   1: f32 row-major out
template <int EPI, int BN>
__global__ __launch_bounds__(256, 4) void gemm_f16(const u16* __restrict__ A,
                                                   const u16* __restrict__ Bt,
                                                   const float* __restrict__ bias,
                                                   u16* __restrict__ outB,
                                                   float* __restrict__ outF,
                                                   int M_, int N_, int K_) {
    constexpr int BK = 32;
    constexpr int NJ = BN / 32;
    __shared__ u16 As[2][128 * BK];
    __shared__ u16 Bs[2][BN * BK];
    const int tid = threadIdx.x;
    const int lane = tid & 63;
    const int wid = tid >> 6;
    const int swz = xcd_swz(blockIdx.y * gridDim.x + blockIdx.x, gridDim.x * gridDim.y);
    const int m0 = (swz / gridDim.x) * 128;
    const int n0 = (swz % gridDim.x) * BN;
    const int wr = (wid >> 1) * 64;
    const int wc = (wid & 1) * (BN / 2);
    const int fr = lane & 15;
    const int fg = 8 * ((lane >> 4) ^ ((fr >> 1) & 3));  // swizzled read col

    const int srow = wid * 32 + (lane >> 2);
    const int srB = wid * (BN / 4) + (lane >> 2);
    const int scol = 8 * ((lane & 3) ^ ((lane >> 3) & 3));  // pre-swizzled source col
    const u16* pa0 = A + (size_t)(m0 + srow) * K_ + scol;
    const u16* pa1 = pa0 + (size_t)16 * K_;
    const u16* pb0 = Bt + (size_t)(n0 + srB) * K_ + scol;
    const u16* pb1 = pb0 + (size_t)16 * K_;
    const int aoff = wid * 1024;
    const int boff = wid * (BN / 4) * BK;

    auto stage = [&](int k0, int buf) {
        gload16(pa0 + k0, &As[buf][aoff]);
        gload16(pa1 + k0, &As[buf][aoff + 512]);
        gload16(pb0 + k0, &Bs[buf][boff]);
        if constexpr (BN == 128) gload16(pb1 + k0, &Bs[buf][boff + 512]);
    };

    f32x4 acc[4][NJ] = {};
    const int nt = K_ / BK;

    stage(0, 0);
    WAITCNT_VM(0);
    RAW_BARRIER();

    for (int t = 0; t < nt; ++t) {
        const int buf = t & 1;
        if (t + 1 < nt) stage((t + 1) * BK, buf ^ 1);
        f16x8 aF[4], bF[NJ];
#pragma unroll
        for (int i = 0; i < 4; ++i) aF[i] = *(const f16x8*)&As[buf][(wr + i * 16 + fr) * BK + fg];
#pragma unroll
        for (int j = 0; j < NJ; ++j) bF[j] = *(const f16x8*)&Bs[buf][(wc + j * 16 + fr) * BK + fg];
#pragma unroll
        for (int i = 0; i < 4; ++i)
#pragma unroll
            for (int j = 0; j < NJ; ++j)
                acc[i][j] = __builtin_amdgcn_mfma_f32_16x16x32_f16(aF[i], bF[j], acc[i][j], 0, 0, 0);
        WAITCNT_VM(0);
        RAW_BARRIER();
    }

    const int g4 = (lane >> 4) * 4;
#pragma unroll
    for (int i = 0; i < 4; ++i) {
#pragma unroll
        for (int j = 0; j < NJ; ++j) {
            const int mb = m0 + wr + i * 16 + g4;
            const int nb = n0 + wc + j * 16 + fr;
            const float bv = bias[nb];
            if constexpr (EPI == 0) {
#pragma unroll
                for (int r = 0; r < 4; ++r)
                    outB[(size_t)(mb + r) * N_ + nb] = f2h(acc[i][j][r] + bv);
            } else {
#pragma unroll
                for (int r = 0; r < 4; ++r)
                    outF[(size_t)(mb + r) * N_ + nb] = acc[i][j][r] + bv;
            }
        }
    }
}

// ---------- split-K fp16 GEMM (MLP2): partial f32 (no bias), blockIdx.z = K half ----------
__global__ __launch_bounds__(256, 4) void gemm_f16_splitk(const u16* __restrict__ A,
                                                          const u16* __restrict__ Bt,
                                                          float* __restrict__ p0,
                                                          float* __restrict__ p1,
                                                          int M_, int N_, int K_) {
    constexpr int BK = 32, BN = 64;
    __shared__ u16 As[2][128 * BK];
    __shared__ u16 Bs[2][BN * BK];
    const int tid = threadIdx.x;
    const int lane = tid & 63;
    const int wid = tid >> 6;
    const int swz = xcd_swz(blockIdx.y * gridDim.x + blockIdx.x, gridDim.x * gridDim.y);
    const int m0 = (swz / gridDim.x) * 128;
    const int n0 = (swz % gridDim.x) * BN;
    const int kBase = blockIdx.z * (K_ >> 1);
    float* dst = blockIdx.z ? p1 : p0;
    const int wr = (wid >> 1) * 64;
    const int wc = (wid & 1) * (BN / 2);
    const int fr = lane & 15;
    const int fg = 8 * ((lane >> 4) ^ ((fr >> 1) & 3));

    const int srow = wid * 32 + (lane >> 2);
    const int srB = wid * (BN / 4) + (lane >> 2);
    const int scol = 8 * ((lane & 3) ^ ((lane >> 3) & 3));
    const u16* pa0 = A + (size_t)(m0 + srow) * K_ + kBase + scol;
    const u16* pa1 = pa0 + (size_t)16 * K_;
    const u16* pb0 = Bt + (size_t)(n0 + srB) * K_ + kBase + scol;
    const int aoff = wid * 1024;
    const int boff = wid * (BN / 4) * BK;

    auto stage = [&](int k0, int buf) {
        gload16(pa0 + k0, &As[buf][aoff]);
        gload16(pa1 + k0, &As[buf][aoff + 512]);
        gload16(pb0 + k0, &Bs[buf][boff]);
    };

    f32x4 acc[4][2] = {};
    const int nt = (K_ >> 1) / BK;

    stage(0, 0);
    WAITCNT_VM(0);
    RAW_BARRIER();

    for (int t = 0; t < nt; ++t) {
        const int buf = t & 1;
        if (t + 1 < nt) stage((t + 1) * BK, buf ^ 1);
        f16x8 aF[4], bF[2];
#pragma unroll
        for (int i = 0; i < 4; ++i) aF[i] = *(const f16x8*)&As[buf][(wr + i * 16 + fr) * BK + fg];
#pragma unroll
        for (int j = 0; j < 2; ++j) bF[j] = *(const f16x8*)&Bs[buf][(wc + j * 16 + fr) * BK + fg];
#pragma unroll
        for (int i = 0; i < 4; ++i)
#pragma unroll
            for (int j = 0; j < 2; ++j)
                acc[i][j] = __builtin_amdgcn_mfma_f32_16x16x32_f16(aF[i], bF[j], acc[i][j], 0, 0, 0);
        WAITCNT_VM(0);
        RAW_BARRIER();
    }

    const int g4 = (lane >> 4) * 4;
#pragma unroll
    for (int i = 0; i < 4; ++i)
#pragma unroll
        for (int j = 0; j < 2; ++j) {
            const int mb = m0 + wr + i * 16 + g4;
            const int nb = n0 + wc + j * 16 + fr;
#pragma unroll
            for (int r = 0; r < 4; ++r)
                dst[(size_t)(mb + r) * N_ + nb] = acc[i][j][r];
        }
}

// ---------- reduce: out = p0 + p1 + bias (f32, vectorized) ----------
__global__ __launch_bounds__(256) void reduce2_bias(const float* __restrict__ p0,
                                                    const float* __restrict__ p1,
                                                    const float* __restrict__ bias,
                                                    float* __restrict__ out, int N_) {
    const size_t i4 = (size_t)blockIdx.x * 256 + threadIdx.x;  // float4 index
    const float4 a = ((const float4*)p0)[i4];
    const float4 b = ((const float4*)p1)[i4];
    const int col4 = (int)(i4 % (N_ / 4));
    const float4 bi = ((const float4*)bias)[col4];
    float4 o;
    o.x = a.x + b.x + bi.x;
    o.y = a.y + b.y + bi.y;
    o.z = a.z + b.z + bi.z;
    o.w = a.w + b.w + bi.w;
    ((float4*)out)[i4] = o;
}

// ------------- fused QKV projection GEMM (fp16, 2-phase dbuf, m-major chunking) -------------
__global__ __launch_bounds__(256, 4) void gemm_qkv(const u16* __restrict__ A,
                                                   const u16* __restrict__ qW,
                                                   const u16* __restrict__ kW,
                                                   const u16* __restrict__ vW,
                                                   const float* __restrict__ bq,
                                                   const float* __restrict__ bk,
                                                   const float* __restrict__ bv,
                                                   u16* __restrict__ qb, u16* __restrict__ kb,
                                                   u16* __restrict__ vtb,
                                                   int M_, int K_) {
    constexpr int BK = 32;
    __shared__ u16 As[2][128 * BK];
    __shared__ u16 Bs[2][64 * BK];
    const int tid = threadIdx.x;
    const int lane = tid & 63;
    const int wid = tid >> 6;
    const int swz = xcd_swz(blockIdx.y * gridDim.x + blockIdx.x, gridDim.x * gridDim.y);
    const int bx = swz % gridDim.x;
    const int region = bx >> 4;  // 0=q 1=k 2=v (block-uniform)
    const int n0 = (bx & 15) * 64;
    const int m0 = (swz / gridDim.x) * 128;
    const int wr = (wid >> 1) * 64;
    const int wc = (wid & 1) * 32;
    const int fr = lane & 15;
    const int fg = 8 * ((lane >> 4) ^ ((fr >> 1) & 3));

    const int srow = wid * 32 + (lane >> 2);
    const int srB = wid * 16 + (lane >> 2);
    const int scol = 8 * ((lane & 3) ^ ((lane >> 3) & 3));

    const u16* B = (region == 0) ? qW : (region == 1) ? kW : vW;
    const u16* pa0 = A + (size_t)(m0 + srow) * K_ + scol;
    const u16* pa1 = pa0 + (size_t)16 * K_;
    const u16* pb = B + (size_t)(n0 + srB) * K_ + scol;
    const int aoff = wid * 1024;
    const int boff = wid * 512;

    auto stage = [&](int k0, int buf) {
        gload16(pa0 + k0, &As[buf][aoff]);
        gload16(pa1 + k0, &As[buf][aoff + 512]);
        gload16(pb + k0, &Bs[buf][boff]);
    };

    f32x4 acc[4][2] = {};
    const int nt = K_ / BK;

    stage(0, 0);
    WAITCNT_VM(0);
    RAW_BARRIER();

    for (int t = 0; t < nt; ++t) {
        const int buf = t & 1;
        if (t + 1 < nt) stage((t + 1) * BK, buf ^ 1);
        f16x8 aF[4], bF[2];
#pragma unroll
        for (int i = 0; i < 4; ++i) aF[i] = *(const f16x8*)&As[buf][(wr + i * 16 + fr) * BK + fg];
#pragma unroll
        for (int j = 0; j < 2; ++j) bF[j] = *(const f16x8*)&Bs[buf][(wc + j * 16 + fr) * BK + fg];
#pragma unroll
        for (int i = 0; i < 4; ++i)
#pragma unroll
            for (int j = 0; j < 2; ++j)
                acc[i][j] = __builtin_amdgcn_mfma_f32_16x16x32_f16(aF[i], bF[j], acc[i][j], 0, 0, 0);
        WAITCNT_VM(0);
        RAW_BARRIER();
    }

    const float* bias = (region == 0) ? bq : (region == 1) ? bk : bv;
    const float scale = (region == 0) ? 32.f : 1.f;
    const int g4 = (lane >> 4) * 4;
#pragma unroll
    for (int i = 0; i < 4; ++i) {
#pragma unroll
        for (int j = 0; j < 2; ++j) {
            const int mb = m0 + wr + i * 16 + g4;
            const int nb = n0 + wc + j * 16 + fr;
            const float bv_ = bias[nb];
            const int h = nb >> 6, e = nb & 63;
            if (region < 2) {
                u16* outp = (region == 0) ? qb : kb;
#pragma unroll
                for (int r = 0; r < 4; ++r) {
                    const int m = mb + r;
                    const size_t idx = ((size_t)((m >> 11) * 16 + h) * 2048 + (m & 2047)) * 64 + e;
                    outp[idx] = f2h((acc[i][j][r] + bv_) * scale);
                }
            } else {
                const int b_ = mb >> 11, np = mb & 2047;
                u16x4 pk;
#pragma unroll
                for (int r = 0; r < 4; ++r) pk[r] = f2h(acc[i][j][r] + bv_);
                *(u16x4*)&vtb[((size_t)(b_ * 16 + h) * 64 + e) * 2048 + np] = pk;
            }
        }
    }
}

// ---------------- flash attention + residual: x2 = x + softmax((q*32) k^T) v ----------------
// 4 waves x 2 q-sets (32 q-rows/wave): K/V LDS reads amortized over 2x MFMA work
// (kernel is DS-pipe-bound per R18). 256 threads, grid 512. KVBLK=64 double-buffered,
// raw barriers + counted vmcnt(4). Swapped QK^T, cvt_pkrtz P-pack, native exp2, setprio.
__global__ __launch_bounds__(256, 2) void attn_kernel(const u16* __restrict__ q,
                                                      const u16* __restrict__ k,
                                                      const u16* __restrict__ vt,
                                                      const float* __restrict__ x,
                                                      float* __restrict__ x2) {
    constexpr int N = 2048, E = 64, KB = 64, NT = N / KB;
    constexpr float L2E = 1.4426950408889634f;
    __shared__ u16 Ks[2][64 * 64];
    __shared__ u16 Vs[2][64 * 64];
    __shared__ unsigned Ps[4][32][36];  // u32 view of P[q=32][k=64] fp16 per wave, row stride 144B

    const int tid = threadIdx.x;
    const int lane = tid & 63;
    const int wid = tid >> 6;  // 0..3
    const int swzb = xcd_swz(blockIdx.x, gridDim.x);
    const int bh = swzb >> 4;
    const int q0 = (swzb & 15) * 128;
    const u16* qh = q + (size_t)bh * N * E;
    const u16* kh = k + (size_t)bh * N * E;
    const u16* vh = vt + (size_t)bh * E * N;

    const int fr = lane & 15;
    const int fgrp = lane >> 4;
    const int fg8 = fgrp * 8;
    int pc[2];
#pragma unroll
    for (int ks = 0; ks < 2; ++ks) pc[ks] = 8 * (((ks << 2) + fgrp) ^ (fr & 7));

    // staging: wave w stages rows [16w, 16w+16) of Ks/Vs (2 gloads each; 4 total/stage)
    const int srow = wid * 16 + (lane >> 3);
    const int swc = 8 * ((lane & 7) ^ (lane >> 3));  // pre-swizzled source col
    u16* dK = &Ks[0][wid * 16 * 64];
    u16* dV = &Vs[0][wid * 16 * 64];
    constexpr int BUFO = 64 * 64;

    // q fragments for both 16-row sets (rows q0 + wid*32 + qs*16 + fr)
    f16x8 qf[2][2];
#pragma unroll
    for (int qs = 0; qs < 2; ++qs)
#pragma unroll
        for (int ks = 0; ks < 2; ++ks)
            qf[qs][ks] = *(const f16x8*)&qh[(size_t)(q0 + wid * 32 + qs * 16 + fr) * E + ks * 32 + fg8];

    auto stage = [&](int t, int buf) {
        const size_t kb = (size_t)t * KB;
        gload16(kh + (kb + srow) * E + swc, dK + buf * BUFO);
        gload16(kh + (kb + srow + 8) * E + swc, dK + buf * BUFO + 8 * 64);
        gload16(vh + (size_t)srow * N + kb + swc, dV + buf * BUFO);
        gload16(vh + (size_t)(srow + 8) * N + kb + swc, dV + buf * BUFO + 8 * 64);
    };

    f32x4 o[2][4] = {};
    float mrow[2] = {-1e30f, -1e30f}, lpart[2] = {0.f, 0.f};

    stage(0, 0);

    for (int t = 0; t < NT; ++t) {
        const int buf = t & 1;
        RAW_BARRIER();  // all waves consumed buf^1 (prev tile)
        if (t + 1 < NT) {
            stage(t + 1, buf ^ 1);
            WAITCNT_VM(4);  // tile t landed; tile t+1's 4 loads stay in flight
        } else {
            WAITCNT_VM(0);
        }
        RAW_BARRIER();  // tile t visible to all waves

        const u16* KK = &Ks[buf][0];
        const u16* VV = &Vs[buf][0];

        // S^T = K . Q^T : lane holds q-rows {q0+wid*32+qs*16+fr}, kpos = fn*16+fgrp*4+r
        f32x4 s[2][4] = {};
        __builtin_amdgcn_s_setprio(1);
#pragma unroll
        for (int fn = 0; fn < 4; ++fn)
#pragma unroll
            for (int ks = 0; ks < 2; ++ks) {
                const f16x8 kf = *(const f16x8*)&KK[(fn * 16 + fr) * 64 + pc[ks]];
                s[0][fn] = __builtin_amdgcn_mfma_f32_16x16x32_f16(kf, qf[0][ks], s[0][fn], 0, 0, 0);
                s[1][fn] = __builtin_amdgcn_mfma_f32_16x16x32_f16(kf, qf[1][ks], s[1][fn], 0, 0, 0);
            }
        __builtin_amdgcn_s_setprio(0);

        float lmax[2];
#pragma unroll
        for (int qs = 0; qs < 2; ++qs) {
            float a = fmaxf(fmaxf(s[qs][0][0], s[qs][0][1]), fmaxf(s[qs][0][2], s[qs][0][3]));
            float b = fmaxf(fmaxf(s[qs][1][0], s[qs][1][1]), fmaxf(s[qs][1][2], s[qs][1][3]));
            float c = fmaxf(fmaxf(s[qs][2][0], s[qs][2][1]), fmaxf(s[qs][2][2], s[qs][2][3]));
            float d = fmaxf(fmaxf(s[qs][3][0], s[qs][3][1]), fmaxf(s[qs][3][2], s[qs][3][3]));
            lmax[qs] = fmaxf(fmaxf(a, b), fmaxf(c, d));
        }
        if (!__all(lmax[0] <= mrow[0] + 8.f && lmax[1] <= mrow[1] + 8.f)) {
#pragma unroll
            for (int qs = 0; qs < 2; ++qs) {
                float m2 = fmaxf(lmax[qs], __shfl_xor(lmax[qs], 16));
                m2 = fmaxf(m2, __shfl_xor(m2, 32));
                const float mnew = fmaxf(mrow[qs], m2);
                const float fac = exp2v((mrow[qs] - mnew) * L2E);
                mrow[qs] = mnew;
                lpart[qs] *= fac;
                float fo[4];
#pragma unroll
                for (int r = 0; r < 4; ++r) fo[r] = __shfl(fac, fgrp * 4 + r);
#pragma unroll
                for (int fe = 0; fe < 4; ++fe)
#pragma unroll
                    for (int r = 0; r < 4; ++r) o[qs][fe][r] *= fo[r];
            }
        }

#pragma unroll
        for (int qs = 0; qs < 2; ++qs) {
            const float nml = -mrow[qs] * L2E;
#pragma unroll
            for (int fn = 0; fn < 4; ++fn) {
                const float p0 = exp2v(fmaf(s[qs][fn][0], L2E, nml));
                const float p1 = exp2v(fmaf(s[qs][fn][1], L2E, nml));
                const float p2 = exp2v(fmaf(s[qs][fn][2], L2E, nml));
                const float p3 = exp2v(fmaf(s[qs][fn][3], L2E, nml));
                lpart[qs] += (p0 + p1) + (p2 + p3);
                uint2 w;
                w.x = cvtpkh(p0, p1);
                w.y = cvtpkh(p2, p3);
                *(uint2*)&Ps[wid][qs * 16 + fr][fn * 8 + fgrp * 2] = w;
            }
        }

        f16x8 pf[2][2];
#pragma unroll
        for (int qs = 0; qs < 2; ++qs) {
            const u16* prow = (const u16*)&Ps[wid][qs * 16 + fr][0];
#pragma unroll
            for (int ks = 0; ks < 2; ++ks) pf[qs][ks] = *(const f16x8*)&prow[ks * 32 + fg8];
        }
        __builtin_amdgcn_s_setprio(1);
#pragma unroll
        for (int fe = 0; fe < 4; ++fe)
#pragma unroll
            for (int ks = 0; ks < 2; ++ks) {
                const f16x8 vf = *(const f16x8*)&VV[(fe * 16 + fr) * 64 + pc[ks]];
                o[0][fe] = __builtin_amdgcn_mfma_f32_16x16x32_f16(pf[0][ks], vf, o[0][fe], 0, 0, 0);
                o[1][fe] = __builtin_amdgcn_mfma_f32_16x16x32_f16(pf[1][ks], vf, o[1][fe], 0, 0, 0);
            }
        __builtin_amdgcn_s_setprio(0);
    }

    const int b_ = bh >> 4, h_ = bh & 15;
#pragma unroll
    for (int qs = 0; qs < 2; ++qs) {
        float lsum = lpart[qs] + __shfl_xor(lpart[qs], 16);
        lsum += __shfl_xor(lsum, 32);
        float rl[4];
#pragma unroll
        for (int r = 0; r < 4; ++r) rl[r] = 1.0f / __shfl(lsum, fgrp * 4 + r);
#pragma unroll
        for (int fe = 0; fe < 4; ++fe)
#pragma unroll
            for (int r = 0; r < 4; ++r) {
                const int npos = q0 + wid * 32 + qs * 16 + fgrp * 4 + r;
                const size_t idx = ((size_t)(b_ * 2048 + npos)) * 1024 + h_ * 64 + fe * 16 + fr;
                x2[idx] = x[idx] + o[qs][fe][r] * rl[r];
            }
    }
}

// ---------------- launch ----------------
extern "C" void kernel_launch(void* const* d_in, const int* in_sizes, int n_in,
                              void* d_out, int out_size, void* d_ws, size_t ws_size,
                              hipStream_t stream) {
    const float* x = (const float*)d_in[0];
    const float* wq = (const float*)d_in[1];
    const float* bq = (const float*)d_in[2];
    const float* wk = (const float*)d_in[3];
    const float* bk = (const float*)d_in[4];
    const float* wv = (const float*)d_in[5];
    const float* bv = (const float*)d_in[6];
    const float* g1 = (const float*)d_in[7];
    const float* b1 = (const float*)d_in[8];
    const float* g2 = (const float*)d_in[9];
    const float* b2 = (const float*)d_in[10];
    const float* w1 = (const float*)d_in[11];
    const float* bw1 = (const float*)d_in[12];
    const float* gf = (const float*)d_in[13];
    const float* bf = (const float*)d_in[14];
    const float* w2 = (const float*)d_in[15];
    const float* bw2 = (const float*)d_in[16];
    float* out = (float*)d_out;

    constexpr int Bc = 2, Nc = 2048, Dc = 1024, Fc = 4096, Mc = 4096;

    char* ws = (char*)d_ws;
    auto alloc = [&](size_t bytes) {
        char* p = ws;
        ws += (bytes + 255) & ~(size_t)255;
        return p;
    };
    u16* wqt = (u16*)alloc((size_t)Dc * Dc * 2);
    u16* wkt = (u16*)alloc((size_t)Dc * Dc * 2);
    u16* wvt = (u16*)alloc((size_t)Dc * Dc * 2);
    u16* w1t = (u16*)alloc((size_t)Dc * Fc * 2);
    u16* w2t = (u16*)alloc((size_t)Fc * Dc * 2);
    // region holds h1, q, k, vT (4 x 8MB); mid (32MB) aliases it after attention
    char* region = (char*)alloc((size_t)Mc * Dc * 2 * 4);
    u16* h1 = (u16*)region;
    u16* qb = h1 + (size_t)Mc * Dc;
    u16* kb = qb + (size_t)Mc * Dc;
    u16* vtb = kb + (size_t)Mc * Dc;
    u16* mid = (u16*)region;
    float* x2 = (float*)alloc((size_t)Mc * Dc * 4);   // dead after LN2 -> reused as p0
    u16* h2 = (u16*)alloc((size_t)Mc * Dc * 2);
    float* p1 = (float*)alloc((size_t)Mc * Dc * 4);
    float* p0 = x2;

    const dim3 tb(32, 8);
    transpose_cast3<<<dim3(Dc / 32, Dc / 32, 3), tb, 0, stream>>>(wq, wqt, wk, wkt, wv, wvt, Dc, Dc);
    transpose_cast<<<dim3(Fc / 32, Dc / 32), tb, 0, stream>>>(w1, w1t, Dc, Fc);
    transpose_cast<<<dim3(Dc / 32, Fc / 32), tb, 0, stream>>>(w2, w2t, Fc, Dc);

    ln_f32_f16<<<Mc, 256, 0, stream>>>(x, g1, b1, h1);

    gemm_qkv<<<dim3(48, Mc / 128), 256, 0, stream>>>(h1, wqt, wkt, wvt, bq, bk, bv,
                                                     qb, kb, vtb, Mc, Dc);

    attn_kernel<<<Bc * 16 * (Nc / 128), 256, 0, stream>>>(qb, kb, vtb, x, x2);

    ln_f32_f16<<<Mc, 256, 0, stream>>>(x2, g2, b2, h2);

    gemm_f16<0, 128><<<dim3(Fc / 128, Mc / 128), 256, 0, stream>>>(h2, w1t, bw1, mid, nullptr, Mc, Fc, Dc);

    ln_relu_f16<<<Mc, 256, 0, stream>>>(mid, gf, bf);

    gemm_f16_splitk<<<dim3(Dc / 64, Mc / 128, 2), 256, 0, stream>>>(mid, w2t, p0, p1, Mc, Dc, Fc);
    reduce2_bias<<<(Mc * Dc) / 1024, 256, 0, stream>>>(p0, p1, bw2, out, Dc);
}

// Round 20
// 260.405 us; speedup vs baseline: 1.0398x; 1.0172x over previous
//
#include <hip/hip_runtime.h>

typedef unsigned short u16;
typedef _Float16 f16;
typedef _Float16 f16x8 __attribute__((ext_vector_type(8)));
typedef float f32x4 __attribute__((ext_vector_type(4)));
typedef unsigned short u16x4 __attribute__((ext_vector_type(4)));
typedef unsigned int u32x4 __attribute__((ext_vector_type(4)));

__device__ __forceinline__ u16 f2h(float f) {
    f16 h = (f16)f;
    return *reinterpret_cast<u16*>(&h);
}
__device__ __forceinline__ float h2f(u16 u) {
    f16 h = *reinterpret_cast<f16*>(&u);
    return (float)h;
}

// 2^x via the native TRANS op, compiler-visible (hazard-safe)
__device__ __forceinline__ float exp2v(float x) { return __builtin_amdgcn_exp2f(x); }

// pack two f32 -> two fp16 in one u32 (RTZ), single VALU op
__device__ __forceinline__ unsigned cvtpkh(float lo, float hi) {
    unsigned r;
    asm("v_cvt_pkrtz_f16_f32 %0, %1, %2" : "=v"(r) : "v"(lo), "v"(hi));
    return r;
}

// async global -> LDS, 16B per lane; LDS dest is wave-uniform base + lane*16
__device__ __forceinline__ void gload16(const u16* g, u16* l) {
    __builtin_amdgcn_global_load_lds((const __attribute__((address_space(1))) unsigned int*)g,
                                     (__attribute__((address_space(3))) unsigned int*)l, 16, 0, 0);
}

#define RAW_BARRIER() __builtin_amdgcn_s_barrier()
#define WAITCNT_VM(N) asm volatile("s_waitcnt vmcnt(" #N ")" ::: "memory")

// XCD-chunked block id remap (bijective: all grids used are multiples of 8)
__device__ __forceinline__ int xcd_swz(int bid, int nwg) {
    return (bid & 7) * (nwg >> 3) + (bid >> 3);
}

// ---------------- transpose + cast fp32 -> fp16, Wt[n][k] = W[k][n]; z selects among 3 ----------------
__global__ void transpose_cast3(const float* __restrict__ W0, u16* __restrict__ T0,
                                const float* __restrict__ W1, u16* __restrict__ T1,
                                const float* __restrict__ W2, u16* __restrict__ T2,
                                int K, int N) {
    __shared__ float t[32][33];
    const float* W = (blockIdx.z == 0) ? W0 : (blockIdx.z == 1) ? W1 : W2;
    u16* Wt = (blockIdx.z == 0) ? T0 : (blockIdx.z == 1) ? T1 : T2;
    const int n0 = blockIdx.x * 32, k0 = blockIdx.y * 32;
    const int tx = threadIdx.x, ty = threadIdx.y;
#pragma unroll
    for (int i = 0; i < 32; i += 8)
        t[ty + i][tx] = W[(size_t)(k0 + ty + i) * N + n0 + tx];
    __syncthreads();
#pragma unroll
    for (int i = 0; i < 32; i += 8)
        Wt[(size_t)(n0 + ty + i) * K + k0 + tx] = f2h(t[tx][ty + i]);
}

__global__ void transpose_cast(const float* __restrict__ W, u16* __restrict__ Wt,
                               int K, int N) {
    __shared__ float t[32][33];
    const int n0 = blockIdx.x * 32, k0 = blockIdx.y * 32;
    const int tx = threadIdx.x, ty = threadIdx.y;
#pragma unroll
    for (int i = 0; i < 32; i += 8)
        t[ty + i][tx] = W[(size_t)(k0 + ty + i) * N + n0 + tx];
    __syncthreads();
#pragma unroll
    for (int i = 0; i < 32; i += 8)
        Wt[(size_t)(n0 + ty + i) * K + k0 + tx] = f2h(t[tx][ty + i]);
}

// ---------------- LayerNorm fp32 -> fp16, D=1024, one block per row ----------------
__global__ __launch_bounds__(256) void ln_f32_f16(const float* __restrict__ in,
                                                  const float* __restrict__ g,
                                                  const float* __restrict__ b,
                                                  u16* __restrict__ out) {
    constexpr int Dl = 1024;
    const int row = blockIdx.x, tid = threadIdx.x;
    const float4 v = *(const float4*)&in[(size_t)row * Dl + tid * 4];
    const float* vp = (const float*)&v;
    float s = v.x + v.y + v.z + v.w;
    float s2 = v.x * v.x + v.y * v.y + v.z * v.z + v.w * v.w;
#pragma unroll
    for (int off = 32; off; off >>= 1) { s += __shfl_xor(s, off); s2 += __shfl_xor(s2, off); }
    __shared__ float red[8];
    const int lane = tid & 63, wid = tid >> 6;
    if (lane == 0) { red[wid] = s; red[4 + wid] = s2; }
    __syncthreads();
    s = red[0] + red[1] + red[2] + red[3];
    s2 = red[4] + red[5] + red[6] + red[7];
    const float mean = s * (1.0f / Dl);
    const float rstd = rsqrtf(s2 * (1.0f / Dl) - mean * mean + 1e-5f);
    u16x4 pk;
#pragma unroll
    for (int i = 0; i < 4; ++i) {
        const int col = tid * 4 + i;
        pk[i] = f2h((vp[i] - mean) * rstd * g[col] + b[col]);
    }
    *(u16x4*)&out[(size_t)row * Dl + tid * 4] = pk;
}

// ---------------- LayerNorm + ReLU in-place on fp16, F=4096 ----------------
__global__ __launch_bounds__(256) void ln_relu_f16(u16* __restrict__ mid,
                                                   const float* __restrict__ g,
                                                   const float* __restrict__ b) {
    constexpr int Fl = 4096;
    const int row = blockIdx.x, tid = threadIdx.x;
    u16* rp = mid + (size_t)row * Fl;
    float v[16];
    u32x4 raw[2];
#pragma unroll
    for (int c = 0; c < 2; ++c) raw[c] = *(const u32x4*)&rp[tid * 16 + c * 8];
#pragma unroll
    for (int c = 0; c < 2; ++c)
#pragma unroll
        for (int j = 0; j < 4; ++j) {
            const unsigned u = raw[c][j];
            v[c * 8 + j * 2] = h2f((u16)(u & 0xffffu));
            v[c * 8 + j * 2 + 1] = h2f((u16)(u >> 16));
        }
    float s = 0.f, s2 = 0.f;
#pragma unroll
    for (int i = 0; i < 16; ++i) { s += v[i]; s2 += v[i] * v[i]; }
#pragma unroll
    for (int off = 32; off; off >>= 1) { s += __shfl_xor(s, off); s2 += __shfl_xor(s2, off); }
    __shared__ float red[8];
    const int lane = tid & 63, wid = tid >> 6;
    if (lane == 0) { red[wid] = s; red[4 + wid] = s2; }
    __syncthreads();
    s = red[0] + red[1] + red[2] + red[3];
    s2 = red[4] + red[5] + red[6] + red[7];
    const float mean = s * (1.0f / Fl);
    const float rstd = rsqrtf(s2 * (1.0f / Fl) - mean * mean + 1e-5f);
    unsigned w[8];
#pragma unroll
    for (int j = 0; j < 8; ++j) {
        const int col = tid * 16 + j * 2;
        const float y0 = fmaxf((v[j * 2] - mean) * rstd * g[col] + b[col], 0.f);
        const float y1 = fmaxf((v[j * 2 + 1] - mean) * rstd * g[col + 1] + b[col + 1], 0.f);
        w[j] = (unsigned)f2h(y0) | ((unsigned)f2h(y1) << 16);
    }
    *(u32x4*)&rp[tid * 16] = *(u32x4*)&w[0];
    *(u32x4*)&rp[tid * 16 + 8] = *(u32x4*)&w[4];
}

// ---------------- fp16 MFMA GEMM, 2-phase dbuf, m-major XCD chunking ----------------
// LDS granule swizzle: source pre-swizzled, LDS dest linear, read col = 8*(fgrp ^ ((fr>>1)&3)).
// EPI 0: fp16 row-major out   1: f32 row-major out
template <int EPI, int BN>
__global__ __launch_bounds__(256, 4) void gemm_f16(const u16* __restrict__ A,
                                                   const u16* __restrict__ Bt,
                                                   const float* __restrict__ bias,
                                                   u16* __restrict__ outB,
                                                   float* __restrict__ outF,
                                                   int M_, int N_, int K_) {
    constexpr int BK = 32;
    constexpr int NJ = BN / 32;
    __shared__ u16 As[2][128 * BK];
    __shared__ u16 Bs[2][BN * BK];
    const int tid = threadIdx.x;
    const int lane = tid & 63;
    const int wid = tid >> 6;
    const int swz = xcd_swz(blockIdx.y * gridDim.x + blockIdx.x, gridDim.x * gridDim.y);
    const int m0 = (swz / gridDim.x) * 128;
    const int n0 = (swz % gridDim.x) * BN;
    const int wr = (wid >> 1) * 64;
    const int wc = (wid & 1) * (BN / 2);
    const int fr = lane & 15;
    const int fg = 8 * ((lane >> 4) ^ ((fr >> 1) & 3));  // swizzled read col

    const int srow = wid * 32 + (lane >> 2);
    const int srB = wid * (BN / 4) + (lane >> 2);
    const int scol = 8 * ((lane & 3) ^ ((lane >> 3) & 3));  // pre-swizzled source col
    const u16* pa0 = A + (size_t)(m0 + srow) * K_ + scol;
    const u16* pa1 = pa0 + (size_t)16 * K_;
    const u16* pb0 = Bt + (size_t)(n0 + srB) * K_ + scol;
    const u16* pb1 = pb0 + (size_t)16 * K_;
    const int aoff = wid * 1024;
    const int boff = wid * (BN / 4) * BK;

    auto stage = [&](int k0, int buf) {
        gload16(pa0 + k0, &As[buf][aoff]);
        gload16(pa1 + k0, &As[buf][aoff + 512]);
        gload16(pb0 + k0, &Bs[buf][boff]);
        if constexpr (BN == 128) gload16(pb1 + k0, &Bs[buf][boff + 512]);
    };

    f32x4 acc[4][NJ] = {};
    const int nt = K_ / BK;

    stage(0, 0);
    WAITCNT_VM(0);
    RAW_BARRIER();

    for (int t = 0; t < nt; ++t) {
        const int buf = t & 1;
        if (t + 1 < nt) stage((t + 1) * BK, buf ^ 1);
        f16x8 aF[4], bF[NJ];
#pragma unroll
        for (int i = 0; i < 4; ++i) aF[i] = *(const f16x8*)&As[buf][(wr + i * 16 + fr) * BK + fg];
#pragma unroll
        for (int j = 0; j < NJ; ++j) bF[j] = *(const f16x8*)&Bs[buf][(wc + j * 16 + fr) * BK + fg];
#pragma unroll
        for (int i = 0; i < 4; ++i)
#pragma unroll
            for (int j = 0; j < NJ; ++j)
                acc[i][j] = __builtin_amdgcn_mfma_f32_16x16x32_f16(aF[i], bF[j], acc[i][j], 0, 0, 0);
        WAITCNT_VM(0);
        RAW_BARRIER();
    }

    const int g4 = (lane >> 4) * 4;
#pragma unroll
    for (int i = 0; i < 4; ++i) {
#pragma unroll
        for (int j = 0; j < NJ; ++j) {
            const int mb = m0 + wr + i * 16 + g4;
            const int nb = n0 + wc + j * 16 + fr;
            const float bv = bias[nb];
            if constexpr (EPI == 0) {
#pragma unroll
                for (int r = 0; r < 4; ++r)
                    outB[(size_t)(mb + r) * N_ + nb] = f2h(acc[i][j][r] + bv);
            } else {
#pragma unroll
                for (int r = 0; r < 4; ++r)
                    outF[(size_t)(mb + r) * N_ + nb] = acc[i][j][r] + bv;
            }
        }
    }
}

// ---------- split-K fp16 GEMM (MLP2): partial f32 (no bias), blockIdx.z = K half ----------
__global__ __launch_bounds__(256, 4) void gemm_f16_splitk(const u16* __restrict__ A,
                                                          const u16* __restrict__ Bt,
                                                          float* __restrict__ p0,
                                                          float* __restrict__ p1,
                                                          int M_, int N_, int K_) {
    constexpr int BK = 32, BN = 64;
    __shared__ u16 As[2][128 * BK];
    __shared__ u16 Bs[2][BN * BK];
    const int tid = threadIdx.x;
    const int lane = tid & 63;
    const int wid = tid >> 6;
    const int swz = xcd_swz(blockIdx.y * gridDim.x + blockIdx.x, gridDim.x * gridDim.y);
    const int m0 = (swz / gridDim.x) * 128;
    const int n0 = (swz % gridDim.x) * BN;
    const int kBase = blockIdx.z * (K_ >> 1);
    float* dst = blockIdx.z ? p1 : p0;
    const int wr = (wid >> 1) * 64;
    const int wc = (wid & 1) * (BN / 2);
    const int fr = lane & 15;
    const int fg = 8 * ((lane >> 4) ^ ((fr >> 1) & 3));

    const int srow = wid * 32 + (lane >> 2);
    const int srB = wid * (BN / 4) + (lane >> 2);
    const int scol = 8 * ((lane & 3) ^ ((lane >> 3) & 3));
    const u16* pa0 = A + (size_t)(m0 + srow) * K_ + kBase + scol;
    const u16* pa1 = pa0 + (size_t)16 * K_;
    const u16* pb0 = Bt + (size_t)(n0 + srB) * K_ + kBase + scol;
    const int aoff = wid * 1024;
    const int boff = wid * (BN / 4) * BK;

    auto stage = [&](int k0, int buf) {
        gload16(pa0 + k0, &As[buf][aoff]);
        gload16(pa1 + k0, &As[buf][aoff + 512]);
        gload16(pb0 + k0, &Bs[buf][boff]);
    };

    f32x4 acc[4][2] = {};
    const int nt = (K_ >> 1) / BK;

    stage(0, 0);
    WAITCNT_VM(0);
    RAW_BARRIER();

    for (int t = 0; t < nt; ++t) {
        const int buf = t & 1;
        if (t + 1 < nt) stage((t + 1) * BK, buf ^ 1);
        f16x8 aF[4], bF[2];
#pragma unroll
        for (int i = 0; i < 4; ++i) aF[i] = *(const f16x8*)&As[buf][(wr + i * 16 + fr) * BK + fg];
#pragma unroll
        for (int j = 0; j < 2; ++j) bF[j] = *(const f16x8*)&Bs[buf][(wc + j * 16 + fr) * BK + fg];
#pragma unroll
        for (int i = 0; i < 4; ++i)
#pragma unroll
            for (int j = 0; j < 2; ++j)
                acc[i][j] = __builtin_amdgcn_mfma_f32_16x16x32_f16(aF[i], bF[j], acc[i][j], 0, 0, 0);
        WAITCNT_VM(0);
        RAW_BARRIER();
    }

    const int g4 = (lane >> 4) * 4;
#pragma unroll
    for (int i = 0; i < 4; ++i)
#pragma unroll
        for (int j = 0; j < 2; ++j) {
            const int mb = m0 + wr + i * 16 + g4;
            const int nb = n0 + wc + j * 16 + fr;
#pragma unroll
            for (int r = 0; r < 4; ++r)
                dst[(size_t)(mb + r) * N_ + nb] = acc[i][j][r];
        }
}

// ---------- reduce: out = p0 + p1 + bias (f32, vectorized) ----------
__global__ __launch_bounds__(256) void reduce2_bias(const float* __restrict__ p0,
                                                    const float* __restrict__ p1,
                                                    const float* __restrict__ bias,
                                                    float* __restrict__ out, int N_) {
    const size_t i4 = (size_t)blockIdx.x * 256 + threadIdx.x;  // float4 index
    const float4 a = ((const float4*)p0)[i4];
    const float4 b = ((const float4*)p1)[i4];
    const int col4 = (int)(i4 % (N_ / 4));
    const float4 bi = ((const float4*)bias)[col4];
    float4 o;
    o.x = a.x + b.x + bi.x;
    o.y = a.y + b.y + bi.y;
    o.z = a.z + b.z + bi.z;
    o.w = a.w + b.w + bi.w;
    ((float4*)out)[i4] = o;
}

// ------------- fused QKV projection GEMM (fp16, 2-phase dbuf, m-major chunking) -------------
// bx 0..15 = q | 16..31 = k | 32..47 = v ; BM=128, BN=64, BK=32
__global__ __launch_bounds__(256, 4) void gemm_qkv(const u16* __restrict__ A,
                                                   const u16* __restrict__ qW,
                                                   const u16* __restrict__ kW,
                                                   const u16* __restrict__ vW,
                                                   const float* __restrict__ bq,
                                                   const float* __restrict__ bk,
                                                   const float* __restrict__ bv,
                                                   u16* __restrict__ qb, u16* __restrict__ kb,
                                                   u16* __restrict__ vtb,
                                                   int M_, int K_) {
    constexpr int BK = 32;
    __shared__ u16 As[2][128 * BK];
    __shared__ u16 Bs[2][64 * BK];
    const int tid = threadIdx.x;
    const int lane = tid & 63;
    const int wid = tid >> 6;
    const int swz = xcd_swz(blockIdx.y * gridDim.x + blockIdx.x, gridDim.x * gridDim.y);
    const int bx = swz % gridDim.x;
    const int region = bx >> 4;  // 0=q 1=k 2=v (block-uniform)
    const int n0 = (bx & 15) * 64;
    const int m0 = (swz / gridDim.x) * 128;
    const int wr = (wid >> 1) * 64;
    const int wc = (wid & 1) * 32;
    const int fr = lane & 15;
    const int fg = 8 * ((lane >> 4) ^ ((fr >> 1) & 3));

    const int srow = wid * 32 + (lane >> 2);
    const int srB = wid * 16 + (lane >> 2);
    const int scol = 8 * ((lane & 3) ^ ((lane >> 3) & 3));

    const u16* B = (region == 0) ? qW : (region == 1) ? kW : vW;
    const u16* pa0 = A + (size_t)(m0 + srow) * K_ + scol;
    const u16* pa1 = pa0 + (size_t)16 * K_;
    const u16* pb = B + (size_t)(n0 + srB) * K_ + scol;
    const int aoff = wid * 1024;
    const int boff = wid * 512;

    auto stage = [&](int k0, int buf) {
        gload16(pa0 + k0, &As[buf][aoff]);
        gload16(pa1 + k0, &As[buf][aoff + 512]);
        gload16(pb + k0, &Bs[buf][boff]);
    };

    f32x4 acc[4][2] = {};
    const int nt = K_ / BK;

    stage(0, 0);
    WAITCNT_VM(0);
    RAW_BARRIER();

    for (int t = 0; t < nt; ++t) {
        const int buf = t & 1;
        if (t + 1 < nt) stage((t + 1) * BK, buf ^ 1);
        f16x8 aF[4], bF[2];
#pragma unroll
        for (int i = 0; i < 4; ++i) aF[i] = *(const f16x8*)&As[buf][(wr + i * 16 + fr) * BK + fg];
#pragma unroll
        for (int j = 0; j < 2; ++j) bF[j] = *(const f16x8*)&Bs[buf][(wc + j * 16 + fr) * BK + fg];
#pragma unroll
        for (int i = 0; i < 4; ++i)
#pragma unroll
            for (int j = 0; j < 2; ++j)
                acc[i][j] = __builtin_amdgcn_mfma_f32_16x16x32_f16(aF[i], bF[j], acc[i][j], 0, 0, 0);
        WAITCNT_VM(0);
        RAW_BARRIER();
    }

    const float* bias = (region == 0) ? bq : (region == 1) ? bk : bv;
    const float scale = (region == 0) ? 32.f : 1.f;
    const int g4 = (lane >> 4) * 4;
#pragma unroll
    for (int i = 0; i < 4; ++i) {
#pragma unroll
        for (int j = 0; j < 2; ++j) {
            const int mb = m0 + wr + i * 16 + g4;
            const int nb = n0 + wc + j * 16 + fr;
            const float bv_ = bias[nb];
            const int h = nb >> 6, e = nb & 63;
            if (region < 2) {
                u16* outp = (region == 0) ? qb : kb;
#pragma unroll
                for (int r = 0; r < 4; ++r) {
                    const int m = mb + r;
                    const size_t idx = ((size_t)((m >> 11) * 16 + h) * 2048 + (m & 2047)) * 64 + e;
                    outp[idx] = f2h((acc[i][j][r] + bv_) * scale);
                }
            } else {
                const int b_ = mb >> 11, np = mb & 2047;
                u16x4 pk;
#pragma unroll
                for (int r = 0; r < 4; ++r) pk[r] = f2h(acc[i][j][r] + bv_);
                *(u16x4*)&vtb[((size_t)(b_ * 16 + h) * 64 + e) * 2048 + np] = pk;
            }
        }
    }
}

// ---------------- flash attention + residual: x2 = x + softmax((q*32) k^T) v ----------------
// fp16 single-term QK^T. 512 threads / 128 q-rows, KVBLK=64 double-buffered with RAW
// barriers + counted vmcnt(2). Swapped QK^T, cvt_pkrtz P-pack, native exp2, setprio.
__global__ __launch_bounds__(512, 4) void attn_kernel(const u16* __restrict__ q,
                                                      const u16* __restrict__ k,
                                                      const u16* __restrict__ vt,
                                                      const float* __restrict__ x,
                                                      float* __restrict__ x2) {
    constexpr int N = 2048, E = 64, KB = 64, NT = N / KB;
    constexpr float L2E = 1.4426950408889634f;
    __shared__ u16 Ks[2][64 * 64];
    __shared__ u16 Vs[2][64 * 64];
    __shared__ unsigned Ps[8][16][36];  // u32 view of P[q=16][k=64] fp16, row stride 144B

    const int tid = threadIdx.x;
    const int lane = tid & 63;
    const int wid = tid >> 6;
    const int swzb = xcd_swz(blockIdx.x, gridDim.x);
    const int bh = swzb >> 4;
    const int q0 = (swzb & 15) * 128;
    const u16* qh = q + (size_t)bh * N * E;
    const u16* kh = k + (size_t)bh * N * E;
    const u16* vh = vt + (size_t)bh * E * N;

    const int fr = lane & 15;
    const int fgrp = lane >> 4;
    const int fg8 = fgrp * 8;
    int pc[2];
#pragma unroll
    for (int ks = 0; ks < 2; ++ks) pc[ks] = 8 * (((ks << 2) + fgrp) ^ (fr & 7));

    const int srow = wid * 8 + (lane >> 3);
    const int swc = 8 * ((lane & 7) ^ (lane >> 3));  // pre-swizzled source col
    u16* dK = &Ks[0][wid * 8 * 64];
    u16* dV = &Vs[0][wid * 8 * 64];
    constexpr int BUFO = 64 * 64;

    f16x8 qf[2];
#pragma unroll
    for (int ks = 0; ks < 2; ++ks)
        qf[ks] = *(const f16x8*)&qh[(size_t)(q0 + wid * 16 + fr) * E + ks * 32 + fg8];

    auto stage = [&](int t, int buf) {
        const size_t kb = (size_t)t * KB;
        gload16(kh + (kb + srow) * E + swc, dK + buf * BUFO);
        gload16(vh + (size_t)srow * N + kb + swc, dV + buf * BUFO);
    };

    f32x4 o[4] = {};
    float mrow = -1e30f, lpart = 0.f;  // per-lane state for q-row (wid*16 + fr)

    stage(0, 0);

    for (int t = 0; t < NT; ++t) {
        const int buf = t & 1;
        RAW_BARRIER();
        if (t + 1 < NT) {
            stage(t + 1, buf ^ 1);
            WAITCNT_VM(2);
        } else {
            WAITCNT_VM(0);
        }
        RAW_BARRIER();

        const u16* KK = &Ks[buf][0];
        const u16* VV = &Vs[buf][0];

        // S^T = K . Q^T : lane holds q-row = wid*16+fr, kpos = fn*16 + fgrp*4 + r
        f32x4 s[4] = {};
        __builtin_amdgcn_s_setprio(1);
#pragma unroll
        for (int fn = 0; fn < 4; ++fn)
#pragma unroll
            for (int ks = 0; ks < 2; ++ks) {
                const f16x8 kf = *(const f16x8*)&KK[(fn * 16 + fr) * 64 + pc[ks]];
                s[fn] = __builtin_amdgcn_mfma_f32_16x16x32_f16(kf, qf[ks], s[fn], 0, 0, 0);
            }
        __builtin_amdgcn_s_setprio(0);

        float lmax = fmaxf(fmaxf(fmaxf(s[0][0], s[0][1]), fmaxf(s[0][2], s[0][3])),
                           fmaxf(fmaxf(s[1][0], s[1][1]), fmaxf(s[1][2], s[1][3])));
        lmax = fmaxf(lmax, fmaxf(fmaxf(fmaxf(s[2][0], s[2][1]), fmaxf(s[2][2], s[2][3])),
                                 fmaxf(fmaxf(s[3][0], s[3][1]), fmaxf(s[3][2], s[3][3]))));
        if (!__all(lmax <= mrow + 8.f)) {
            float m2 = fmaxf(lmax, __shfl_xor(lmax, 16));
            m2 = fmaxf(m2, __shfl_xor(m2, 32));
            const float mnew = fmaxf(mrow, m2);
            const float fac = exp2v((mrow - mnew) * L2E);
            mrow = mnew;
            lpart *= fac;
            float fo[4];
#pragma unroll
            for (int r = 0; r < 4; ++r) fo[r] = __shfl(fac, fgrp * 4 + r);
#pragma unroll
            for (int fe = 0; fe < 4; ++fe)
#pragma unroll
                for (int r = 0; r < 4; ++r) o[fe][r] *= fo[r];
        }

        const float nml = -mrow * L2E;
#pragma unroll
        for (int fn = 0; fn < 4; ++fn) {
            const float p0 = exp2v(fmaf(s[fn][0], L2E, nml));
            const float p1 = exp2v(fmaf(s[fn][1], L2E, nml));
            const float p2 = exp2v(fmaf(s[fn][2], L2E, nml));
            const float p3 = exp2v(fmaf(s[fn][3], L2E, nml));
            lpart += (p0 + p1) + (p2 + p3);
            uint2 w;
            w.x = cvtpkh(p0, p1);
            w.y = cvtpkh(p2, p3);
            *(uint2*)&Ps[wid][fr][fn * 8 + fgrp * 2] = w;
        }

        const u16* prow = (const u16*)&Ps[wid][fr][0];
        f16x8 pf[2];
#pragma unroll
        for (int ks = 0; ks < 2; ++ks) pf[ks] = *(const f16x8*)&prow[ks * 32 + fg8];
        __builtin_amdgcn_s_setprio(1);
#pragma unroll
        for (int fe = 0; fe < 4; ++fe)
#pragma unroll
            for (int ks = 0; ks < 2; ++ks) {
                const f16x8 vf = *(const f16x8*)&VV[(fe * 16 + fr) * 64 + pc[ks]];
                o[fe] = __builtin_amdgcn_mfma_f32_16x16x32_f16(pf[ks], vf, o[fe], 0, 0, 0);
            }
        __builtin_amdgcn_s_setprio(0);
    }

    float lsum = lpart + __shfl_xor(lpart, 16);
    lsum += __shfl_xor(lsum, 32);
    float rl[4];
#pragma unroll
    for (int r = 0; r < 4; ++r) rl[r] = 1.0f / __shfl(lsum, fgrp * 4 + r);

    const int b_ = bh >> 4, h_ = bh & 15;
#pragma unroll
    for (int fe = 0; fe < 4; ++fe)
#pragma unroll
        for (int r = 0; r < 4; ++r) {
            const int npos = q0 + wid * 16 + fgrp * 4 + r;
            const size_t idx = ((size_t)(b_ * 2048 + npos)) * 1024 + h_ * 64 + fe * 16 + fr;
            x2[idx] = x[idx] + o[fe][r] * rl[r];
        }
}

// ---------------- launch ----------------
extern "C" void kernel_launch(void* const* d_in, const int* in_sizes, int n_in,
                              void* d_out, int out_size, void* d_ws, size_t ws_size,
                              hipStream_t stream) {
    const float* x = (const float*)d_in[0];
    const float* wq = (const float*)d_in[1];
    const float* bq = (const float*)d_in[2];
    const float* wk = (const float*)d_in[3];
    const float* bk = (const float*)d_in[4];
    const float* wv = (const float*)d_in[5];
    const float* bv = (const float*)d_in[6];
    const float* g1 = (const float*)d_in[7];
    const float* b1 = (const float*)d_in[8];
    const float* g2 = (const float*)d_in[9];
    const float* b2 = (const float*)d_in[10];
    const float* w1 = (const float*)d_in[11];
    const float* bw1 = (const float*)d_in[12];
    const float* gf = (const float*)d_in[13];
    const float* bf = (const float*)d_in[14];
    const float* w2 = (const float*)d_in[15];
    const float* bw2 = (const float*)d_in[16];
    float* out = (float*)d_out;

    constexpr int Bc = 2, Nc = 2048, Dc = 1024, Fc = 4096, Mc = 4096;

    char* ws = (char*)d_ws;
    auto alloc = [&](size_t bytes) {
        char* p = ws;
        ws += (bytes + 255) & ~(size_t)255;
        return p;
    };
    u16* wqt = (u16*)alloc((size_t)Dc * Dc * 2);
    u16* wkt = (u16*)alloc((size_t)Dc * Dc * 2);
    u16* wvt = (u16*)alloc((size_t)Dc * Dc * 2);
    u16* w1t = (u16*)alloc((size_t)Dc * Fc * 2);
    u16* w2t = (u16*)alloc((size_t)Fc * Dc * 2);
    // region holds h1, q, k, vT (4 x 8MB); mid (32MB) aliases it after attention
    char* region = (char*)alloc((size_t)Mc * Dc * 2 * 4);
    u16* h1 = (u16*)region;
    u16* qb = h1 + (size_t)Mc * Dc;
    u16* kb = qb + (size_t)Mc * Dc;
    u16* vtb = kb + (size_t)Mc * Dc;
    u16* mid = (u16*)region;
    float* x2 = (float*)alloc((size_t)Mc * Dc * 4);   // dead after LN2 -> reused as p0
    u16* h2 = (u16*)alloc((size_t)Mc * Dc * 2);
    float* p1 = (float*)alloc((size_t)Mc * Dc * 4);
    float* p0 = x2;

    const dim3 tb(32, 8);
    transpose_cast3<<<dim3(Dc / 32, Dc / 32, 3), tb, 0, stream>>>(wq, wqt, wk, wkt, wv, wvt, Dc, Dc);
    transpose_cast<<<dim3(Fc / 32, Dc / 32), tb, 0, stream>>>(w1, w1t, Dc, Fc);
    transpose_cast<<<dim3(Dc / 32, Fc / 32), tb, 0, stream>>>(w2, w2t, Fc, Dc);

    ln_f32_f16<<<Mc, 256, 0, stream>>>(x, g1, b1, h1);

    gemm_qkv<<<dim3(48, Mc / 128), 256, 0, stream>>>(h1, wqt, wkt, wvt, bq, bk, bv,
                                                     qb, kb, vtb, Mc, Dc);

    attn_kernel<<<Bc * 16 * (Nc / 128), 512, 0, stream>>>(qb, kb, vtb, x, x2);

    ln_f32_f16<<<Mc, 256, 0, stream>>>(x2, g2, b2, h2);

    gemm_f16<0, 128><<<dim3(Fc / 128, Mc / 128), 256, 0, stream>>>(h2, w1t, bw1, mid, nullptr, Mc, Fc, Dc);

    ln_relu_f16<<<Mc, 256, 0, stream>>>(mid, gf, bf);

    gemm_f16_splitk<<<dim3(Dc / 64, Mc / 128, 2), 256, 0, stream>>>(mid, w2t, p0, p1, Mc, Dc, Fc);
    reduce2_bias<<<(Mc * Dc) / 1024, 256, 0, stream>>>(p0, p1, bw2, out, Dc);
}